// Round 1
// baseline (3141.184 us; speedup 1.0000x reference)
//
#include <hip/hip_runtime.h>

typedef __attribute__((ext_vector_type(8))) short bf16x8;
typedef __attribute__((ext_vector_type(4))) float f32x4;
typedef unsigned short ushort_t;
typedef unsigned int uint_t;

#define VOCAB 5000
#define HID   512
#define B_    64
#define SEQ_  256
#define H3    1536
#define NPAD  5120
#define GREC  32
#define JS    16

__device__ __forceinline__ ushort_t f2bf(float f){
  uint_t u = __float_as_uint(f);
  u = u + 0x7fffu + ((u >> 16) & 1u);
  return (ushort_t)(u >> 16);
}
__device__ __forceinline__ float bf2f(ushort_t s){
  return __uint_as_float(((uint_t)s) << 16);
}
__device__ __forceinline__ float xload(const float* p){ return *p; }
__device__ __forceinline__ float xload(const ushort_t* p){ return bf2f(*p); }

// ---------------- P1: transpose W_ih (1536 x 5000) -> W_ihT (5000 x 1536) ----------
__global__ void k_transpose(const float* __restrict__ W, float* __restrict__ WT){
  __shared__ float tile[32][33];
  const int bv = blockIdx.x * 32;   // vocab
  const int bg = blockIdx.y * 32;   // 3H
  const int tx = threadIdx.x, ty = threadIdx.y; // 32x8
  #pragma unroll
  for(int r = 0; r < 32; r += 8){
    int g = bg + ty + r, v = bv + tx;
    tile[ty + r][tx] = (v < VOCAB) ? W[(size_t)g * VOCAB + v] : 0.f;
  }
  __syncthreads();
  #pragma unroll
  for(int r = 0; r < 32; r += 8){
    int v = bv + ty + r, g = bg + tx;
    if(v < VOCAB) WT[(size_t)v * H3 + g] = tile[tx][ty + r];
  }
}

// ---------------- P1b: W_out (5000x512) -> bf16 padded (5120x512) ------------------
__global__ void k_cvt_wout(const float* __restrict__ W, ushort_t* __restrict__ WP){
  int idx = (blockIdx.x * 256 + threadIdx.x) * 4;
  if(idx >= NPAD * HID) return;
  float x0 = 0.f, x1 = 0.f, x2 = 0.f, x3 = 0.f;
  if(idx < VOCAB * HID){
    const float4 v = *(const float4*)(W + idx);
    x0 = v.x; x1 = v.y; x2 = v.z; x3 = v.w;
  }
  ushort4 o; o.x = f2bf(x0); o.y = f2bf(x1); o.z = f2bf(x2); o.w = f2bf(x3);
  *(ushort4*)(WP + idx) = o;
}

// ---------------- P2: gather x_proj[s,b,:] = W_ihT[X[b,s]] + b_ih ------------------
template<typename T>
__global__ void k_gather(const int* __restrict__ X, const float* __restrict__ WT,
                         const float* __restrict__ bih, T* __restrict__ xp){
  const int sb = blockIdx.x;            // s*64 + b
  const int s = sb >> 6, b = sb & 63;
  const int x = X[b * SEQ_ + s];
  const float4* src = (const float4*)(WT + (size_t)x * H3);
  const float4* bi  = (const float4*)bih;
  for(int i = threadIdx.x; i < H3 / 4; i += 256){
    float4 v = src[i], c = bi[i];
    float a0 = v.x + c.x, a1 = v.y + c.y, a2 = v.z + c.z, a3 = v.w + c.w;
    if constexpr (sizeof(T) == 4){
      float4 o; o.x = a0; o.y = a1; o.z = a2; o.w = a3;
      ((float4*)(xp + (size_t)sb * H3))[i] = o;
    } else {
      ushort4 o; o.x = f2bf(a0); o.y = f2bf(a1); o.z = f2bf(a2); o.w = f2bf(a3);
      ((ushort4*)(xp + (size_t)sb * H3))[i] = o;
    }
  }
}

// ---------------- R: persistent GRU recurrence, 32 WGs x 256 thr -------------------
// WG g owns j in [g*16, g*16+16): rows {j, 512+j, 1024+j} of W_hh (48 rows) in LDS.
// Wave w handles batches [16w,16w+16). Lane: j = jbase + (lane&15); 4 batches
// b = 16w + 4*(lane>>4) + i  (matches MFMA C/D layout col=lane&15,row=(lane>>4)*4+i).
template<typename XT>
__global__ void __launch_bounds__(256, 1) k_rec(
    const float* __restrict__ Whh, const float* __restrict__ bhh,
    const float* __restrict__ state, const XT* __restrict__ xp,
    ushort_t* __restrict__ hbuf,   // 2 x [64][512] bf16 (double buffer)
    ushort_t* __restrict__ Y,      // [256][64][512] bf16
    float* __restrict__ hT,        // d_out tail
    uint_t* flags)                 // [32], zeroed before launch
{
  __shared__ ushort_t Wl[48][520]; // +8 pad -> 2-way (free) bank aliasing on b128
  __shared__ float bl[48];
  const int g = blockIdx.x, jbase = g * JS, tid = threadIdx.x;

  for(int idx = tid; idx < 48 * 512; idx += 256){
    int r = idx >> 9, c = idx & 511;
    int gate = r >> 4, jj = r & 15;
    Wl[r][c] = f2bf(Whh[((size_t)(gate * HID + jbase + jj)) * HID + c]);
  }
  if(tid < 48) bl[tid] = bhh[(tid >> 4) * HID + jbase + (tid & 15)];

  const int lane = tid & 63, wv = tid >> 6;
  const int l15 = lane & 15, lhi = lane >> 4;
  const int j = jbase + l15;
  const int bband = wv * 16;

  float hprev[4]; int brow[4];
  #pragma unroll
  for(int i = 0; i < 4; i++){
    brow[i] = bband + lhi * 4 + i;
    hprev[i] = state[brow[i] * HID + j];
  }
  #pragma unroll
  for(int i = 0; i < 4; i++) hbuf[brow[i] * HID + j] = f2bf(hprev[i]);
  __threadfence();
  __syncthreads();
  if(tid == 0) __hip_atomic_store(flags + g, 1u, __ATOMIC_RELEASE, __HIP_MEMORY_SCOPE_AGENT);

  for(int t = 0; t < SEQ_; ++t){
    const ushort_t* hin  = hbuf + (t & 1) * (B_ * HID);
    ushort_t*       hout = hbuf + ((t + 1) & 1) * (B_ * HID);

    // prefetch gi (independent of h) before the flag wait
    float gir[4], giz[4], gin_[4];
    const XT* xr = xp + (size_t)t * B_ * H3;
    #pragma unroll
    for(int i = 0; i < 4; i++){
      const XT* p = xr + (size_t)brow[i] * H3 + j;
      gir[i] = xload(p); giz[i] = xload(p + HID); gin_[i] = xload(p + 2 * HID);
    }

    // wait: everyone has published h^t (flag >= t+1)
    if(tid < GREC){
      const uint_t need = (uint_t)(t + 1);
      int guard = 0;
      while(__hip_atomic_load(flags + tid, __ATOMIC_ACQUIRE, __HIP_MEMORY_SCOPE_AGENT) < need){
        __builtin_amdgcn_s_sleep(1);
        if(++guard > 100000) break;   // fail loud (wrong answer) instead of hanging
      }
    }
    __syncthreads();
    __threadfence();  // acquire: invalidate caches before reading hin

    // GEMM: gh_slice = H(64x512) @ Wl^T(512x48)
    f32x4 acc0 = {0.f,0.f,0.f,0.f}, acc1 = {0.f,0.f,0.f,0.f}, acc2 = {0.f,0.f,0.f,0.f};
    const ushort_t* ab = hin + (size_t)(bband + l15) * HID + 8 * lhi;
    bf16x8 af[16];
    #pragma unroll
    for(int kk = 0; kk < 16; kk++) af[kk] = *(const bf16x8*)(ab + kk * 32);
    #pragma unroll
    for(int kk = 0; kk < 16; kk++){
      const int kc = kk * 32 + 8 * lhi;
      bf16x8 b0 = *(const bf16x8*)&Wl[l15][kc];
      bf16x8 b1 = *(const bf16x8*)&Wl[16 + l15][kc];
      bf16x8 b2 = *(const bf16x8*)&Wl[32 + l15][kc];
      acc0 = __builtin_amdgcn_mfma_f32_16x16x32_bf16(af[kk], b0, acc0, 0, 0, 0);
      acc1 = __builtin_amdgcn_mfma_f32_16x16x32_bf16(af[kk], b1, acc1, 0, 0, 0);
      acc2 = __builtin_amdgcn_mfma_f32_16x16x32_bf16(af[kk], b2, acc2, 0, 0, 0);
    }

    const float br_ = bl[l15], bz_ = bl[16 + l15], bn_ = bl[32 + l15];
    #pragma unroll
    for(int i = 0; i < 4; i++){
      float r = 1.f / (1.f + expf(-(gir[i] + acc0[i] + br_)));
      float z = 1.f / (1.f + expf(-(giz[i] + acc1[i] + bz_)));
      float n = tanhf(gin_[i] + r * (acc2[i] + bn_));
      float hn = (1.f - z) * n + z * hprev[i];
      hprev[i] = hn;
      ushort_t hb = f2bf(hn);
      hout[(size_t)brow[i] * HID + j] = hb;
      Y[(size_t)t * B_ * HID + (size_t)brow[i] * HID + j] = hb;
      if(t == SEQ_ - 1) hT[brow[i] * HID + j] = hn;
    }
    __threadfence();
    __syncthreads();
    if(tid == 0) __hip_atomic_store(flags + g, (uint_t)(t + 2), __ATOMIC_RELEASE, __HIP_MEMORY_SCOPE_AGENT);
  }
}

// ---------------- C: out = Y(16384x512) @ W_outP^T(512x5120) + b_out ---------------
__global__ void __launch_bounds__(256) k_outgemm(
    const ushort_t* __restrict__ Y, const ushort_t* __restrict__ WP,
    const float* __restrict__ bout, float* __restrict__ out)
{
  __shared__ ushort_t At[128][40];
  __shared__ ushort_t Bt[128][40];
  const int tid = threadIdx.x;
  const int sb0 = blockIdx.x * 128, n0 = blockIdx.y * 128;
  const int lane = tid & 63, wv = tid >> 6;
  const int l15 = lane & 15, lhi = lane >> 4;
  const int wm = wv >> 1, wn = wv & 1;

  f32x4 acc[4][4];
  #pragma unroll
  for(int a = 0; a < 4; a++)
    #pragma unroll
    for(int b = 0; b < 4; b++) acc[a][b] = (f32x4){0.f,0.f,0.f,0.f};

  for(int kt = 0; kt < 16; ++kt){
    const int k0 = kt * 32;
    __syncthreads();
    #pragma unroll
    for(int hh = 0; hh < 2; ++hh){
      int idx = tid + hh * 256;          // 0..511 over 128 rows x 4 segs
      int row = idx >> 2, seg = idx & 3;
      int4 va = *(const int4*)(Y  + (size_t)(sb0 + row) * HID + k0 + seg * 8);
      *(int4*)&At[row][seg * 8] = va;
      int4 vb = *(const int4*)(WP + (size_t)(n0 + row) * HID + k0 + seg * 8);
      *(int4*)&Bt[row][seg * 8] = vb;
    }
    __syncthreads();
    bf16x8 a[4], b[4];
    #pragma unroll
    for(int mi = 0; mi < 4; mi++) a[mi] = *(const bf16x8*)&At[wm * 64 + mi * 16 + l15][8 * lhi];
    #pragma unroll
    for(int ni = 0; ni < 4; ni++) b[ni] = *(const bf16x8*)&Bt[wn * 64 + ni * 16 + l15][8 * lhi];
    #pragma unroll
    for(int mi = 0; mi < 4; mi++)
      #pragma unroll
      for(int ni = 0; ni < 4; ni++)
        acc[mi][ni] = __builtin_amdgcn_mfma_f32_16x16x32_bf16(a[mi], b[ni], acc[mi][ni], 0, 0, 0);
  }

  #pragma unroll
  for(int mi = 0; mi < 4; mi++){
    #pragma unroll
    for(int ni = 0; ni < 4; ni++){
      int v = n0 + wn * 64 + ni * 16 + l15;
      if(v < VOCAB){
        float bb = bout[v];
        #pragma unroll
        for(int i = 0; i < 4; i++){
          int sb = sb0 + wm * 64 + mi * 16 + lhi * 4 + i;
          out[(size_t)sb * VOCAB + v] = acc[mi][ni][i] + bb;
        }
      }
    }
  }
}

extern "C" void kernel_launch(void* const* d_in, const int* in_sizes, int n_in,
                              void* d_out, int out_size, void* d_ws, size_t ws_size,
                              hipStream_t stream)
{
  const int*   X     = (const int*)  d_in[0];
  const float* state = (const float*)d_in[1];
  const float* Wih   = (const float*)d_in[2];
  const float* Whh   = (const float*)d_in[3];
  const float* bih   = (const float*)d_in[4];
  const float* bhh   = (const float*)d_in[5];
  const float* Wout  = (const float*)d_in[6];
  const float* bout  = (const float*)d_in[7];
  float* out = (float*)d_out;
  float* hT  = out + (size_t)SEQ_ * B_ * VOCAB;

  char* ws = (char*)d_ws;
  const size_t off_WihT  = 4096;
  const size_t off_WoutP = off_WihT  + (size_t)VOCAB * H3  * sizeof(float);
  const size_t off_Y     = off_WoutP + (size_t)NPAD  * HID * sizeof(ushort_t);
  const size_t off_h     = off_Y     + (size_t)SEQ_ * B_ * HID * sizeof(ushort_t);
  const size_t off_xp    = off_h     + (size_t)2 * B_ * HID * sizeof(ushort_t);
  const size_t need_f32  = off_xp    + (size_t)SEQ_ * B_ * H3 * sizeof(float);
  const bool xp32 = (ws_size >= need_f32);

  float*    WihT  = (float*)   (ws + off_WihT);
  ushort_t* WoutP = (ushort_t*)(ws + off_WoutP);
  ushort_t* Ybuf  = (ushort_t*)(ws + off_Y);
  ushort_t* hbuf  = (ushort_t*)(ws + off_h);
  uint_t*   flags = (uint_t*)  ws;

  hipMemsetAsync(d_ws, 0, 4096, stream);
  hipLaunchKernelGGL(k_transpose, dim3(157, 48), dim3(32, 8), 0, stream, Wih, WihT);
  hipLaunchKernelGGL(k_cvt_wout, dim3((NPAD * HID / 4 + 255) / 256), dim3(256), 0, stream, Wout, WoutP);
  if(xp32){
    float* xp = (float*)(ws + off_xp);
    hipLaunchKernelGGL(k_gather<float>, dim3(SEQ_ * B_), dim3(256), 0, stream, X, WihT, bih, xp);
    hipLaunchKernelGGL(k_rec<float>, dim3(GREC), dim3(256), 0, stream,
                       Whh, bhh, state, xp, hbuf, Ybuf, hT, flags);
  } else {
    ushort_t* xp = (ushort_t*)(ws + off_xp);
    hipLaunchKernelGGL(k_gather<ushort_t>, dim3(SEQ_ * B_), dim3(256), 0, stream, X, WihT, bih, xp);
    hipLaunchKernelGGL(k_rec<ushort_t>, dim3(GREC), dim3(256), 0, stream,
                       Whh, bhh, state, xp, hbuf, Ybuf, hT, flags);
  }
  hipLaunchKernelGGL(k_outgemm, dim3(128, 40), dim3(256), 0, stream, Ybuf, WoutP, bout, out);
}

// Round 2
// 1633.463 us; speedup vs baseline: 1.9230x; 1.9230x over previous
//
#include <hip/hip_runtime.h>

typedef __attribute__((ext_vector_type(8))) short bf16x8;
typedef __attribute__((ext_vector_type(4))) float f32x4;
typedef unsigned short ushort_t;
typedef unsigned int uint_t;

#define VOCAB 5000
#define HID   512
#define B_    64
#define SEQ_  256
#define H3    1536
#define NPAD  5120
#define GREC  32
#define JS    16

__device__ __forceinline__ ushort_t f2bf(float f){
  uint_t u = __float_as_uint(f);
  u = u + 0x7fffu + ((u >> 16) & 1u);
  return (ushort_t)(u >> 16);
}
__device__ __forceinline__ float bf2f(ushort_t s){
  return __uint_as_float(((uint_t)s) << 16);
}
__device__ __forceinline__ float xload(const float* p){ return *p; }
__device__ __forceinline__ float xload(const ushort_t* p){ return bf2f(*p); }

// ---- coherence-point (sc0 sc1) access helpers: no fences, no wbl2 ----
__device__ __forceinline__ void sys_store_u32(uint_t* p, uint_t v){
  asm volatile("global_store_dword %0, %1, off sc0 sc1" :: "v"(p), "v"(v) : "memory");
}
__device__ __forceinline__ uint_t sys_load_u32(const uint_t* p){
  uint_t v;
  asm volatile("global_load_dword %0, %1, off sc0 sc1\n\t"
               "s_waitcnt vmcnt(0)" : "=v"(v) : "v"(p) : "memory");
  return v;
}
__device__ __forceinline__ void sys_store_u16(ushort_t* p, ushort_t v){
  uint_t vv = v;
  asm volatile("global_store_short %0, %1, off sc0 sc1" :: "v"(p), "v"(vv) : "memory");
}

// ---------------- P1: transpose W_ih (1536 x 5000) -> W_ihT (5000 x 1536) ----------
__global__ void k_transpose(const float* __restrict__ W, float* __restrict__ WT){
  __shared__ float tile[32][33];
  const int bv = blockIdx.x * 32;   // vocab
  const int bg = blockIdx.y * 32;   // 3H
  const int tx = threadIdx.x, ty = threadIdx.y; // 32x8
  #pragma unroll
  for(int r = 0; r < 32; r += 8){
    int g = bg + ty + r, v = bv + tx;
    tile[ty + r][tx] = (v < VOCAB) ? W[(size_t)g * VOCAB + v] : 0.f;
  }
  __syncthreads();
  #pragma unroll
  for(int r = 0; r < 32; r += 8){
    int v = bv + ty + r, g = bg + tx;
    if(v < VOCAB) WT[(size_t)v * H3 + g] = tile[tx][ty + r];
  }
}

// ---------------- P1b: W_out (5000x512) -> bf16 padded (5120x512) ------------------
__global__ void k_cvt_wout(const float* __restrict__ W, ushort_t* __restrict__ WP){
  int idx = (blockIdx.x * 256 + threadIdx.x) * 4;
  if(idx >= NPAD * HID) return;
  float x0 = 0.f, x1 = 0.f, x2 = 0.f, x3 = 0.f;
  if(idx < VOCAB * HID){
    const float4 v = *(const float4*)(W + idx);
    x0 = v.x; x1 = v.y; x2 = v.z; x3 = v.w;
  }
  ushort4 o; o.x = f2bf(x0); o.y = f2bf(x1); o.z = f2bf(x2); o.w = f2bf(x3);
  *(ushort4*)(WP + idx) = o;
}

// ---------------- P2: gather x_proj[s,b,:] = W_ihT[X[b,s]] + b_ih ------------------
template<typename T>
__global__ void k_gather(const int* __restrict__ X, const float* __restrict__ WT,
                         const float* __restrict__ bih, T* __restrict__ xp){
  const int sb = blockIdx.x;            // s*64 + b
  const int s = sb >> 6, b = sb & 63;
  const int x = X[b * SEQ_ + s];
  const float4* src = (const float4*)(WT + (size_t)x * H3);
  const float4* bi  = (const float4*)bih;
  for(int i = threadIdx.x; i < H3 / 4; i += 256){
    float4 v = src[i], c = bi[i];
    float a0 = v.x + c.x, a1 = v.y + c.y, a2 = v.z + c.z, a3 = v.w + c.w;
    if constexpr (sizeof(T) == 4){
      float4 o; o.x = a0; o.y = a1; o.z = a2; o.w = a3;
      ((float4*)(xp + (size_t)sb * H3))[i] = o;
    } else {
      ushort4 o; o.x = f2bf(a0); o.y = f2bf(a1); o.z = f2bf(a2); o.w = f2bf(a3);
      ((ushort4*)(xp + (size_t)sb * H3))[i] = o;
    }
  }
}

// ---------------- R: persistent GRU recurrence, 32 WGs x 256 thr -------------------
// Cross-WG handoff entirely via sc0/sc1 coherence-point ops; NO fences (no wbl2).
template<typename XT>
__global__ void __launch_bounds__(256, 1) k_rec(
    const float* __restrict__ Whh, const float* __restrict__ bhh,
    const float* __restrict__ state, const XT* __restrict__ xp,
    ushort_t* __restrict__ hbuf,   // 2 x [64][512] bf16 (double buffer)
    ushort_t* __restrict__ Y,      // [256][64][512] bf16
    float* __restrict__ hT,        // d_out tail
    uint_t* flags)                 // [32], zeroed before launch
{
  __shared__ ushort_t Wl[48][520];
  __shared__ float bl[48];
  const int g = blockIdx.x, jbase = g * JS, tid = threadIdx.x;

  for(int idx = tid; idx < 48 * 512; idx += 256){
    int r = idx >> 9, c = idx & 511;
    int gate = r >> 4, jj = r & 15;
    Wl[r][c] = f2bf(Whh[((size_t)(gate * HID + jbase + jj)) * HID + c]);
  }
  if(tid < 48) bl[tid] = bhh[(tid >> 4) * HID + jbase + (tid & 15)];

  const int lane = tid & 63, wv = tid >> 6;
  const int l15 = lane & 15, lhi = lane >> 4;
  const int j = jbase + l15;
  const int bband = wv * 16;

  float hprev[4]; int brow[4];
  #pragma unroll
  for(int i = 0; i < 4; i++){
    brow[i] = bband + lhi * 4 + i;
    hprev[i] = state[brow[i] * HID + j];
  }
  #pragma unroll
  for(int i = 0; i < 4; i++) sys_store_u16(hbuf + brow[i] * HID + j, f2bf(hprev[i]));
  asm volatile("s_waitcnt vmcnt(0)" ::: "memory");
  __syncthreads();
  if(tid == 0) sys_store_u32(flags + g, 1u);

  for(int t = 0; t < SEQ_; ++t){
    const ushort_t* hin  = hbuf + (t & 1) * (B_ * HID);
    ushort_t*       hout = hbuf + ((t + 1) & 1) * (B_ * HID);

    // prefetch gi (independent of h) before the flag wait
    float gir[4], giz[4], gin_[4];
    const XT* xr = xp + (size_t)t * B_ * H3;
    #pragma unroll
    for(int i = 0; i < 4; i++){
      const XT* p = xr + (size_t)brow[i] * H3 + j;
      gir[i] = xload(p); giz[i] = xload(p + HID); gin_[i] = xload(p + 2 * HID);
    }

    // wait: everyone has published h^t (flag >= t+1)
    if(tid < GREC){
      const uint_t need = (uint_t)(t + 1);
      int guard = 0;
      while(sys_load_u32(flags + tid) < need){
        if(++guard > 100000) break;   // fail loud (wrong answer) instead of hanging
      }
    }
    __syncthreads();

    // read h^t fragments straight from the coherence point
    int4 tmp[16];
    const char* abase = (const char*)(hin + (size_t)(bband + l15) * HID + 8 * lhi);
    #define LDH(i, off) asm volatile("global_load_dwordx4 %0, %1, off offset:" #off " sc0 sc1" \
                                     : "=v"(tmp[i]) : "v"(abase) : "memory");
    LDH(0,0)   LDH(1,64)   LDH(2,128)  LDH(3,192)
    LDH(4,256) LDH(5,320)  LDH(6,384)  LDH(7,448)
    LDH(8,512) LDH(9,576)  LDH(10,640) LDH(11,704)
    LDH(12,768) LDH(13,832) LDH(14,896) LDH(15,960)
    #undef LDH
    asm volatile("s_waitcnt vmcnt(0)" ::: "memory");
    __builtin_amdgcn_sched_barrier(0);

    // GEMM: gh_slice = H(64x512) @ Wl^T(512x48)
    f32x4 acc0 = {0.f,0.f,0.f,0.f}, acc1 = {0.f,0.f,0.f,0.f}, acc2 = {0.f,0.f,0.f,0.f};
    #pragma unroll
    for(int kk = 0; kk < 16; kk++){
      bf16x8 a = __builtin_bit_cast(bf16x8, tmp[kk]);
      const int kc = kk * 32 + 8 * lhi;
      bf16x8 b0 = *(const bf16x8*)&Wl[l15][kc];
      bf16x8 b1 = *(const bf16x8*)&Wl[16 + l15][kc];
      bf16x8 b2 = *(const bf16x8*)&Wl[32 + l15][kc];
      acc0 = __builtin_amdgcn_mfma_f32_16x16x32_bf16(a, b0, acc0, 0, 0, 0);
      acc1 = __builtin_amdgcn_mfma_f32_16x16x32_bf16(a, b1, acc1, 0, 0, 0);
      acc2 = __builtin_amdgcn_mfma_f32_16x16x32_bf16(a, b2, acc2, 0, 0, 0);
    }

    const float br_ = bl[l15], bz_ = bl[16 + l15], bn_ = bl[32 + l15];
    #pragma unroll
    for(int i = 0; i < 4; i++){
      float r = 1.f / (1.f + expf(-(gir[i] + acc0[i] + br_)));
      float z = 1.f / (1.f + expf(-(giz[i] + acc1[i] + bz_)));
      float n = tanhf(gin_[i] + r * (acc2[i] + bn_));
      float hn = (1.f - z) * n + z * hprev[i];
      hprev[i] = hn;
      ushort_t hb = f2bf(hn);
      sys_store_u16(hout + (size_t)brow[i] * HID + j, hb);
      Y[(size_t)t * B_ * HID + (size_t)brow[i] * HID + j] = hb;
      if(t == SEQ_ - 1) hT[brow[i] * HID + j] = hn;
    }
    asm volatile("s_waitcnt vmcnt(0)" ::: "memory");
    __syncthreads();
    if(tid == 0) sys_store_u32(flags + g, (uint_t)(t + 2));
  }
}

// ---------------- C: out = Y(16384x512) @ W_outP^T(512x5120) + b_out ---------------
__global__ void __launch_bounds__(256) k_outgemm(
    const ushort_t* __restrict__ Y, const ushort_t* __restrict__ WP,
    const float* __restrict__ bout, float* __restrict__ out)
{
  __shared__ ushort_t At[128][40];
  __shared__ ushort_t Bt[128][40];
  const int tid = threadIdx.x;
  const int sb0 = blockIdx.x * 128, n0 = blockIdx.y * 128;
  const int lane = tid & 63, wv = tid >> 6;
  const int l15 = lane & 15, lhi = lane >> 4;
  const int wm = wv >> 1, wn = wv & 1;

  f32x4 acc[4][4];
  #pragma unroll
  for(int a = 0; a < 4; a++)
    #pragma unroll
    for(int b = 0; b < 4; b++) acc[a][b] = (f32x4){0.f,0.f,0.f,0.f};

  for(int kt = 0; kt < 16; ++kt){
    const int k0 = kt * 32;
    __syncthreads();
    #pragma unroll
    for(int hh = 0; hh < 2; ++hh){
      int idx = tid + hh * 256;          // 0..511 over 128 rows x 4 segs
      int row = idx >> 2, seg = idx & 3;
      int4 va = *(const int4*)(Y  + (size_t)(sb0 + row) * HID + k0 + seg * 8);
      *(int4*)&At[row][seg * 8] = va;
      int4 vb = *(const int4*)(WP + (size_t)(n0 + row) * HID + k0 + seg * 8);
      *(int4*)&Bt[row][seg * 8] = vb;
    }
    __syncthreads();
    bf16x8 a[4], b[4];
    #pragma unroll
    for(int mi = 0; mi < 4; mi++) a[mi] = *(const bf16x8*)&At[wm * 64 + mi * 16 + l15][8 * lhi];
    #pragma unroll
    for(int ni = 0; ni < 4; ni++) b[ni] = *(const bf16x8*)&Bt[wn * 64 + ni * 16 + l15][8 * lhi];
    #pragma unroll
    for(int mi = 0; mi < 4; mi++)
      #pragma unroll
      for(int ni = 0; ni < 4; ni++)
        acc[mi][ni] = __builtin_amdgcn_mfma_f32_16x16x32_bf16(a[mi], b[ni], acc[mi][ni], 0, 0, 0);
  }

  #pragma unroll
  for(int mi = 0; mi < 4; mi++){
    #pragma unroll
    for(int ni = 0; ni < 4; ni++){
      int v = n0 + wn * 64 + ni * 16 + l15;
      if(v < VOCAB){
        float bb = bout[v];
        #pragma unroll
        for(int i = 0; i < 4; i++){
          int sb = sb0 + wm * 64 + mi * 16 + lhi * 4 + i;
          out[(size_t)sb * VOCAB + v] = acc[mi][ni][i] + bb;
        }
      }
    }
  }
}

extern "C" void kernel_launch(void* const* d_in, const int* in_sizes, int n_in,
                              void* d_out, int out_size, void* d_ws, size_t ws_size,
                              hipStream_t stream)
{
  const int*   X     = (const int*)  d_in[0];
  const float* state = (const float*)d_in[1];
  const float* Wih   = (const float*)d_in[2];
  const float* Whh   = (const float*)d_in[3];
  const float* bih   = (const float*)d_in[4];
  const float* bhh   = (const float*)d_in[5];
  const float* Wout  = (const float*)d_in[6];
  const float* bout  = (const float*)d_in[7];
  float* out = (float*)d_out;
  float* hT  = out + (size_t)SEQ_ * B_ * VOCAB;

  char* ws = (char*)d_ws;
  const size_t off_WihT  = 4096;
  const size_t off_WoutP = off_WihT  + (size_t)VOCAB * H3  * sizeof(float);
  const size_t off_Y     = off_WoutP + (size_t)NPAD  * HID * sizeof(ushort_t);
  const size_t off_h     = off_Y     + (size_t)SEQ_ * B_ * HID * sizeof(ushort_t);
  const size_t off_xp    = off_h     + (size_t)2 * B_ * HID * sizeof(ushort_t);
  const size_t need_f32  = off_xp    + (size_t)SEQ_ * B_ * H3 * sizeof(float);
  const bool xp32 = (ws_size >= need_f32);

  float*    WihT  = (float*)   (ws + off_WihT);
  ushort_t* WoutP = (ushort_t*)(ws + off_WoutP);
  ushort_t* Ybuf  = (ushort_t*)(ws + off_Y);
  ushort_t* hbuf  = (ushort_t*)(ws + off_h);
  uint_t*   flags = (uint_t*)  ws;

  hipMemsetAsync(d_ws, 0, 4096, stream);
  hipLaunchKernelGGL(k_transpose, dim3(157, 48), dim3(32, 8), 0, stream, Wih, WihT);
  hipLaunchKernelGGL(k_cvt_wout, dim3((NPAD * HID / 4 + 255) / 256), dim3(256), 0, stream, Wout, WoutP);
  if(xp32){
    float* xp = (float*)(ws + off_xp);
    hipLaunchKernelGGL(k_gather<float>, dim3(SEQ_ * B_), dim3(256), 0, stream, X, WihT, bih, xp);
    hipLaunchKernelGGL(k_rec<float>, dim3(GREC), dim3(256), 0, stream,
                       Whh, bhh, state, xp, hbuf, Ybuf, hT, flags);
  } else {
    ushort_t* xp = (ushort_t*)(ws + off_xp);
    hipLaunchKernelGGL(k_gather<ushort_t>, dim3(SEQ_ * B_), dim3(256), 0, stream, X, WihT, bih, xp);
    hipLaunchKernelGGL(k_rec<ushort_t>, dim3(GREC), dim3(256), 0, stream,
                       Whh, bhh, state, xp, hbuf, Ybuf, hT, flags);
  }
  hipLaunchKernelGGL(k_outgemm, dim3(128, 40), dim3(256), 0, stream, Ybuf, WoutP, bout, out);
}